// Round 10
// baseline (1217.823 us; speedup 1.0000x reference)
//
#include <hip/hip_runtime.h>
#include <math.h>

#define FDIM 128
#define NEG_SLOPE 0.2f
#define LN_EPS 1e-5f

// ---------------- CSR build ----------------

__global__ void k_zero(int* __restrict__ p, int n) {
    int i = blockIdx.x * blockDim.x + threadIdx.x;
    if (i < n) p[i] = 0;
}

__global__ void k_deg(const int* __restrict__ ei, int E, int* __restrict__ deg) {
    int i = blockIdx.x * blockDim.x + threadIdx.x;
    if (i < E) atomicAdd(&deg[ei[E + i]], 1);
}

// single-block exclusive scan over N elements (N ~ 100k), 1024 threads
__global__ __launch_bounds__(1024) void k_scan(const int* __restrict__ deg,
                                               int* __restrict__ offs, int N) {
    __shared__ int tl[1024];
    int tid = threadIdx.x;
    int chunk = (N + 1023) >> 10;
    int s = tid * chunk;
    int e = s + chunk; if (e > N) e = N;
    int sum = 0;
    for (int i = s; i < e; ++i) sum += deg[i];
    tl[tid] = sum;
    __syncthreads();
    for (int off = 1; off < 1024; off <<= 1) {
        int v = (tid >= off) ? tl[tid - off] : 0;
        __syncthreads();
        tl[tid] += v;
        __syncthreads();
    }
    int run = tl[tid] - sum;  // exclusive prefix for this thread's chunk
    for (int i = s; i < e; ++i) { offs[i] = run; run += deg[i]; }
    if (tid == 1023) offs[N] = run;  // == E
}

__global__ void k_fill(const int* __restrict__ ei, int E, const int* __restrict__ offs,
                       int* __restrict__ cur, int* __restrict__ csr_src) {
    int i = blockIdx.x * blockDim.x + threadIdx.x;
    if (i < E) {
        int dst = ei[E + i];
        int p = offs[dst] + atomicAdd(&cur[dst], 1);
        csr_src[p] = ei[i];
    }
}

// ---------------- xl / xr linear transforms (baseline, known-good) ----------------
__global__ __launch_bounds__(256) void k_xlxr(const float* __restrict__ x,
        const float* __restrict__ Wl, const float* __restrict__ bl,
        const float* __restrict__ Wr, const float* __restrict__ br,
        float* __restrict__ xl, float* __restrict__ xr, int N) {
    __shared__ __align__(16) float xs[32][128];
    int tid = threadIdx.x;
    int row0 = blockIdx.x * 32;
    for (int v = tid; v < 32 * 32; v += 256) {   // 1024 float4
        int r = v >> 5, c4 = v & 31;
        int gr = row0 + r;
        float4 val = (gr < N) ? ((const float4*)x)[(size_t)gr * 32 + c4]
                              : make_float4(0.f, 0.f, 0.f, 0.f);
        *(float4*)&xs[r][c4 * 4] = val;
    }
    __syncthreads();

    int cg = tid & 63;   // 64 col groups of 4 -> 256 cols
    int rg = tid >> 6;   // 4 row groups of 8
    int j = cg * 4;
    const float* W = (j < 128) ? (Wl + j) : (Wr + (j - 128));
    const float* bp = (j < 128) ? (bl + j) : (br + (j - 128));
    float4 acc[8];
#pragma unroll
    for (int r = 0; r < 8; ++r) acc[r] = make_float4(0.f, 0.f, 0.f, 0.f);

    for (int k = 0; k < 128; ++k) {
        float4 w = *(const float4*)(W + (size_t)k * 128);
#pragma unroll
        for (int r = 0; r < 8; ++r) {
            float s = xs[rg * 8 + r][k];  // wave-uniform -> LDS broadcast
            acc[r].x += s * w.x; acc[r].y += s * w.y;
            acc[r].z += s * w.z; acc[r].w += s * w.w;
        }
    }
    float4 b = *(const float4*)bp;
    float* outb = (j < 128) ? xl : xr;
    int jj = (j < 128) ? j : (j - 128);
#pragma unroll
    for (int r = 0; r < 8; ++r) {
        int gr = row0 + rg * 8 + r;
        if (gr < N) {
            float4 v = make_float4(acc[r].x + b.x, acc[r].y + b.y,
                                   acc[r].z + b.z, acc[r].w + b.w);
            *(float4*)&outb[(size_t)gr * 128 + jj] = v;
        }
    }
}

// ---------------- GATv2 aggregation: one wave per node, online softmax ----------
// 4 independent online-softmax chains over edge residues mod 4 (exact merge at
// the end) + quad load issue for 4x memory-level parallelism.
#define GAT_UPD(m_, l_, a_, xv_) { \
    float sx_ = xrv.x + xv_.x; \
    float sy_ = xrv.y + xv_.y; \
    sx_ = (sx_ > 0.f) ? sx_ : NEG_SLOPE * sx_; \
    sy_ = (sy_ > 0.f) ? sy_ : NEG_SLOPE * sy_; \
    float p_ = sx_ * av.x + sy_ * av.y; \
    p_ += __shfl_xor(p_, 1); \
    p_ += __shfl_xor(p_, 2); \
    p_ += __shfl_xor(p_, 4); \
    float mn_ = fmaxf(m_, p_); \
    float sc_ = __expf(m_ - mn_); \
    float w_  = __expf(p_ - mn_); \
    l_ = l_ * sc_ + w_; \
    a_.x = a_.x * sc_ + w_ * xv_.x; \
    a_.y = a_.y * sc_ + w_ * xv_.y; \
    m_ = mn_; }

__global__ __launch_bounds__(256) void k_gat(const float* __restrict__ xl,
        const float* __restrict__ xr, const float* __restrict__ att,
        const float* __restrict__ bias,
        const int* __restrict__ offs, const int* __restrict__ csr_src,
        float* __restrict__ h, int N) {
    int wave = threadIdx.x >> 6;
    int lane = threadIdx.x & 63;
    int node = blockIdx.x * 4 + wave;
    if (node >= N) return;

    int c0 = lane * 2;  // channel pair; head = c0>>4, 8 lanes per head
    float2 xrv = *(const float2*)&xr[(size_t)node * 128 + c0];
    float2 av  = *(const float2*)&att[c0];

    float mA = -3.0e38f, lA = 0.f, mB = -3.0e38f, lB = 0.f;
    float mC = -3.0e38f, lC = 0.f, mD = -3.0e38f, lD = 0.f;
    float2 aA = make_float2(0.f, 0.f), aB = make_float2(0.f, 0.f);
    float2 aC = make_float2(0.f, 0.f), aD = make_float2(0.f, 0.f);

    int e0 = offs[node], e1 = offs[node + 1];
    int i = e0;
    for (; i + 3 < e1; i += 4) {
        int s0 = csr_src[i];
        int s1 = csr_src[i + 1];
        int s2 = csr_src[i + 2];
        int s3 = csr_src[i + 3];
        float2 x0 = *(const float2*)&xl[(size_t)s0 * 128 + c0];
        float2 x1 = *(const float2*)&xl[(size_t)s1 * 128 + c0];
        float2 x2 = *(const float2*)&xl[(size_t)s2 * 128 + c0];
        float2 x3 = *(const float2*)&xl[(size_t)s3 * 128 + c0];
        GAT_UPD(mA, lA, aA, x0);
        GAT_UPD(mB, lB, aB, x1);
        GAT_UPD(mC, lC, aC, x2);
        GAT_UPD(mD, lD, aD, x3);
    }
    for (; i < e1; ++i) {
        int s0 = csr_src[i];
        float2 x0 = *(const float2*)&xl[(size_t)s0 * 128 + c0];
        GAT_UPD(mA, lA, aA, x0);
    }

    float mn1 = fmaxf(mA, mB);
    float sA = __expf(mA - mn1), sB = __expf(mB - mn1);
    float l1 = lA * sA + lB * sB;
    float2 a1 = make_float2(aA.x * sA + aB.x * sB, aA.y * sA + aB.y * sB);

    float mn2 = fmaxf(mC, mD);
    float sC = __expf(mC - mn2), sD = __expf(mD - mn2);
    float l2 = lC * sC + lD * sD;
    float2 a2 = make_float2(aC.x * sC + aD.x * sD, aC.y * sC + aD.y * sD);

    float mn = fmaxf(mn1, mn2);
    float s1m = __expf(mn1 - mn), s2m = __expf(mn2 - mn);
    float l = l1 * s1m + l2 * s2m;
    float2 acc = make_float2(a1.x * s1m + a2.x * s2m,
                             a1.y * s1m + a2.y * s2m);

    float inv = (l > 0.f) ? (1.f / l) : 0.f;
    float2 bv = *(const float2*)&bias[c0];
    float2 o = make_float2(acc.x * inv + bv.x, acc.y * inv + bv.y);
    *(float2*)&h[(size_t)node * 128 + c0] = o;
}

// ---------------- fused FFN: wave-local barrier-free pipeline -------------------
// 16 rows/block, 4 waves; wave w owns rows 4w..4w+3 end-to-end:
//   load+LN1 -> GEMM1(lane: 8 contig cols) -> SiLU -> GEMM2(lane: 2 cols)
//   -> +residual -> LN2. All LDS regions are wave-private -> NO __syncthreads.
// GEMM1: 32 FMA / 4 broadcast b128 reads; GEMM2: 32 FMA / 4 reads (was 8/4, 4/4).
__global__ __launch_bounds__(256) void k_ffn(const float* __restrict__ h,
        const float* __restrict__ g1, const float* __restrict__ bn1,
        const float* __restrict__ W1, const float* __restrict__ bW1,
        const float* __restrict__ W2, const float* __restrict__ bW2,
        const float* __restrict__ g2, const float* __restrict__ bn2,
        float* __restrict__ out, int N) {
    __shared__ __align__(16) float hs[16][128];
    __shared__ __align__(16) float ts[16][132];   // +4 pad: LN-phase write spread
    __shared__ __align__(16) float us[16][512];
    int tid = threadIdx.x;
    int row0 = blockIdx.x * 16;
    int wave = tid >> 6, lane = tid & 63;
    int g = tid >> 4, l16 = tid & 15, c = l16 * 8;   // group g -> row g; g>>2 == wave

    // ---- Phase 1 (wave-local): load h row g, LN1 -> ts row g
    {
        int gr = row0 + g;
        float4 a = make_float4(0.f, 0.f, 0.f, 0.f);
        float4 b = make_float4(0.f, 0.f, 0.f, 0.f);
        if (gr < N) {
            a = ((const float4*)h)[(size_t)gr * 32 + l16 * 2];
            b = ((const float4*)h)[(size_t)gr * 32 + l16 * 2 + 1];
        }
        *(float4*)&hs[g][c] = a;
        *(float4*)&hs[g][c + 4] = b;
        float sum = a.x + a.y + a.z + a.w + b.x + b.y + b.z + b.w;
        float sq  = a.x*a.x + a.y*a.y + a.z*a.z + a.w*a.w
                  + b.x*b.x + b.y*b.y + b.z*b.z + b.w*b.w;
#pragma unroll
        for (int msk = 1; msk < 16; msk <<= 1) {
            sum += __shfl_xor(sum, msk);
            sq  += __shfl_xor(sq,  msk);
        }
        float mu = sum * (1.f / 128.f);
        float var = sq * (1.f / 128.f) - mu * mu;
        float rstd = rsqrtf(var + LN_EPS);
        float xv[8] = {a.x, a.y, a.z, a.w, b.x, b.y, b.z, b.w};
        float o[8];
#pragma unroll
        for (int u = 0; u < 8; ++u)
            o[u] = (xv[u] - mu) * rstd * g1[c + u] + bn1[c + u];
        *(float4*)&ts[g][c]     = make_float4(o[0], o[1], o[2], o[3]);
        *(float4*)&ts[g][c + 4] = make_float4(o[4], o[5], o[6], o[7]);
    }
    // no barrier: everything below touches only this wave's rows

    int r0 = wave * 4;    // this wave's rows
    int c8 = lane * 8;    // GEMM1 columns c8..c8+7

    // ---- GEMM1: rows r0..r0+3 x cols c8..c8+7, K=128
    float acc[4][8];
#pragma unroll
    for (int r = 0; r < 4; ++r)
#pragma unroll
        for (int u = 0; u < 8; ++u) acc[r][u] = 0.f;

    for (int k4 = 0; k4 < 32; ++k4) {
        int kb = k4 * 4;
        float4 t4[4];
        t4[0] = *(const float4*)&ts[r0 + 0][kb];
        t4[1] = *(const float4*)&ts[r0 + 1][kb];
        t4[2] = *(const float4*)&ts[r0 + 2][kb];
        t4[3] = *(const float4*)&ts[r0 + 3][kb];
        const float* tv = (const float*)t4;   // tv[r*4+kk], static after unroll
#pragma unroll
        for (int kk = 0; kk < 4; ++kk) {
            const float* wr = W1 + (size_t)(kb + kk) * 512 + c8;
            float4 wa = *(const float4*)wr;
            float4 wb = *(const float4*)(wr + 4);
#pragma unroll
            for (int r = 0; r < 4; ++r) {
                float t = tv[r * 4 + kk];
                acc[r][0] += t * wa.x; acc[r][1] += t * wa.y;
                acc[r][2] += t * wa.z; acc[r][3] += t * wa.w;
                acc[r][4] += t * wb.x; acc[r][5] += t * wb.y;
                acc[r][6] += t * wb.z; acc[r][7] += t * wb.w;
            }
        }
    }

    // ---- bias + SiLU -> us rows r0..r0+3, cols c8..c8+7
    {
        float4 b1a = *(const float4*)&bW1[c8];
        float4 b1b = *(const float4*)&bW1[c8 + 4];
        float bb[8] = {b1a.x, b1a.y, b1a.z, b1a.w, b1b.x, b1b.y, b1b.z, b1b.w};
#pragma unroll
        for (int r = 0; r < 4; ++r) {
            float o[8];
#pragma unroll
            for (int u = 0; u < 8; ++u) {
                float v = acc[r][u] + bb[u];
                o[u] = v * __builtin_amdgcn_rcpf(1.f + __expf(-v));
            }
            *(float4*)&us[r0 + r][c8]     = make_float4(o[0], o[1], o[2], o[3]);
            *(float4*)&us[r0 + r][c8 + 4] = make_float4(o[4], o[5], o[6], o[7]);
        }
    }

    // ---- GEMM2: rows r0..r0+3 x cols c2..c2+1, K=512
    int c2 = lane * 2;
    float acc2[4][2];
#pragma unroll
    for (int r = 0; r < 4; ++r) { acc2[r][0] = 0.f; acc2[r][1] = 0.f; }

    for (int k4 = 0; k4 < 128; ++k4) {
        int kb = k4 * 4;
        float4 u4[4];
        u4[0] = *(const float4*)&us[r0 + 0][kb];
        u4[1] = *(const float4*)&us[r0 + 1][kb];
        u4[2] = *(const float4*)&us[r0 + 2][kb];
        u4[3] = *(const float4*)&us[r0 + 3][kb];
        const float* uv = (const float*)u4;
#pragma unroll
        for (int kk = 0; kk < 4; ++kk) {
            float2 wv = *(const float2*)&W2[(size_t)(kb + kk) * 128 + c2];
#pragma unroll
            for (int r = 0; r < 4; ++r) {
                float u = uv[r * 4 + kk];
                acc2[r][0] += u * wv.x;
                acc2[r][1] += u * wv.y;
            }
        }
    }

    // ---- bias + residual -> ts rows r0..r0+3 (reuse)
    {
        float2 b2 = *(const float2*)&bW2[c2];
#pragma unroll
        for (int r = 0; r < 4; ++r) {
            int row = r0 + r;
            float2 hres = *(const float2*)&hs[row][c2];
            ts[row][c2]     = acc2[r][0] + b2.x + hres.x;
            ts[row][c2 + 1] = acc2[r][1] + b2.y + hres.y;
        }
    }

    // ---- LN2 + store: group g reads row g (written by this wave above)
    {
        float4 a = *(float4*)&ts[g][c];
        float4 b = *(float4*)&ts[g][c + 4];
        float sum = a.x + a.y + a.z + a.w + b.x + b.y + b.z + b.w;
        float sq  = a.x*a.x + a.y*a.y + a.z*a.z + a.w*a.w
                  + b.x*b.x + b.y*b.y + b.z*b.z + b.w*b.w;
#pragma unroll
        for (int msk = 1; msk < 16; msk <<= 1) {
            sum += __shfl_xor(sum, msk);
            sq  += __shfl_xor(sq,  msk);
        }
        float mu = sum * (1.f / 128.f);
        float var = sq * (1.f / 128.f) - mu * mu;
        float rstd = rsqrtf(var + LN_EPS);
        int gr = row0 + g;
        if (gr < N) {
            float xv[8] = {a.x, a.y, a.z, a.w, b.x, b.y, b.z, b.w};
#pragma unroll
            for (int u = 0; u < 8; ++u) {
                out[(size_t)gr * 128 + c + u] =
                    (xv[u] - mu) * rstd * g2[c + u] + bn2[c + u];
            }
        }
    }
}

// ---------------- launch ----------------
extern "C" void kernel_launch(void* const* d_in, const int* in_sizes, int n_in,
                              void* d_out, int out_size, void* d_ws, size_t ws_size,
                              hipStream_t stream) {
    const float* x        = (const float*)d_in[0];
    const int*   ei       = (const int*)  d_in[1];
    const float* Wl       = (const float*)d_in[2];
    const float* bl       = (const float*)d_in[3];
    const float* Wr       = (const float*)d_in[4];
    const float* br       = (const float*)d_in[5];
    const float* att      = (const float*)d_in[6];
    const float* bias_gat = (const float*)d_in[7];
    const float* g1       = (const float*)d_in[8];
    const float* bn1      = (const float*)d_in[9];
    const float* W1       = (const float*)d_in[10];
    const float* bW1      = (const float*)d_in[11];
    const float* W2       = (const float*)d_in[12];
    const float* bW2      = (const float*)d_in[13];
    const float* g2       = (const float*)d_in[14];
    const float* bn2      = (const float*)d_in[15];

    int N = in_sizes[0] / 128;   // B*N
    int E = in_sizes[1] / 2;

    char* w = (char*)d_ws;
    float* xl  = (float*)w; w += (size_t)N * 128 * 4;
    float* xr  = (float*)w; w += (size_t)N * 128 * 4;
    float* hb  = (float*)w; w += (size_t)N * 128 * 4;
    int* offs  = (int*)w;   w += (size_t)(N + 1) * 4;
    int* deg   = (int*)w;   w += (size_t)N * 4;
    int* csr   = (int*)w;   w += (size_t)E * 4;
    float* out = (float*)d_out;

    int eb = (E + 255) / 256;
    int nb = (N + 255) / 256;

    k_zero<<<nb, 256, 0, stream>>>(deg, N);
    k_deg<<<eb, 256, 0, stream>>>(ei, E, deg);
    k_scan<<<1, 1024, 0, stream>>>(deg, offs, N);
    k_zero<<<nb, 256, 0, stream>>>(deg, N);
    k_fill<<<eb, 256, 0, stream>>>(ei, E, offs, deg, csr);

    k_xlxr<<<(N + 31) / 32, 256, 0, stream>>>(x, Wl, bl, Wr, br, xl, xr, N);
    k_gat<<<(N + 3) / 4, 256, 0, stream>>>(xl, xr, att, bias_gat, offs, csr, hb, N);
    k_ffn<<<(N + 15) / 16, 256, 0, stream>>>(hb, g1, bn1, W1, bW1, W2, bW2,
                                             g2, bn2, out, N);
}